// Round 9
// baseline (401.223 us; speedup 1.0000x reference)
//
#include <hip/hip_runtime.h>
#include <hip/hip_bf16.h>
#include <stdint.h>

#define Bdim 64
#define Sdim 512
#define Hdim 768
#define G3   2304

typedef float f32x4 __attribute__((ext_vector_type(4)));
typedef short s16x8 __attribute__((ext_vector_type(8)));
typedef short s16x4 __attribute__((ext_vector_type(4)));

__device__ __forceinline__ float bf2f(unsigned short u){
  union { unsigned int i; float f; } c; c.i = ((unsigned int)u) << 16; return c.f;
}
__device__ __forceinline__ unsigned short f2bf(float f){
  union { float f; unsigned int i; } c; c.f = f;
  unsigned int x = c.i;
  return (unsigned short)((x + 0x7fffu + ((x >> 16) & 1u)) >> 16);
}
__device__ __forceinline__ float fast_tanh(float x){
  float e = __expf(2.f * x);
  return 1.f - 2.f / (e + 1.f);
}
__device__ __forceinline__ float fast_sigmoid(float x){
  return 1.f / (1.f + __expf(-x));
}
// async global->LDS, 16B per lane; lds base must be wave-uniform
__device__ __forceinline__ void gload16(const void* g, void* l){
  __builtin_amdgcn_global_load_lds((const __attribute__((address_space(1))) void*)g,
                                   (__attribute__((address_space(3))) void*)l, 16, 0, 0);
}

// ---------------- merged prep: 5 transposes + 5 bf16 casts in one dispatch ----------------
__global__ __launch_bounds__(256) void k_prep(const float* __restrict__ SE, unsigned short* __restrict__ SEb,
                                              const float* __restrict__ ws_, unsigned short* __restrict__ wsbT,
                                              const float* __restrict__ wd1, unsigned short* __restrict__ wd1T,
                                              const float* __restrict__ wd,  unsigned short* __restrict__ wdT,
                                              const float* __restrict__ wa,  unsigned short* __restrict__ waT,
                                              const float* __restrict__ whs, unsigned short* __restrict__ whsT,
                                              const float* __restrict__ w_ih, unsigned short* __restrict__ w_ihb,
                                              const float* __restrict__ w_hh, unsigned short* __restrict__ w_hhb,
                                              const float* __restrict__ sr,  unsigned short* __restrict__ srb,
                                              const float* __restrict__ asp, unsigned short* __restrict__ aspb){
  __shared__ float tile[32][33];
  int bid = blockIdx.x;
  if (bid < 2880) {
    int which = bid / 576, r = bid % 576;
    const float* src; unsigned short* dst;
    switch (which) {
      case 0: src = ws_; dst = wsbT; break;
      case 1: src = wd1; dst = wd1T; break;
      case 2: src = wd;  dst = wdT;  break;
      case 3: src = wa;  dst = waT;  break;
      default: src = whs; dst = whsT; break;
    }
    int bx = (r % 24) * 32, by = (r / 24) * 32;
    int tx = threadIdx.x % 32, ty = threadIdx.x / 32;
    for (int j = ty; j < 32; j += 8) tile[j][tx] = src[(size_t)(by + j) * Hdim + bx + tx];
    __syncthreads();
    for (int j = ty; j < 32; j += 8) dst[(size_t)(bx + j) * Hdim + by + tx] = f2bf(tile[tx][j]);
    return;
  }
  bid -= 2880;
  const float* s; unsigned short* d; int j;
  if      (bid < 12288) { s = SE;   d = SEb;   j = bid * 256 + threadIdx.x; }
  else if (bid < 13152) { s = w_ih; d = w_ihb; j = (bid - 12288) * 256 + threadIdx.x; }
  else if (bid < 14016) { s = w_hh; d = w_hhb; j = (bid - 13152) * 256 + threadIdx.x; }
  else if (bid < 14040) { s = sr;   d = srb;   j = (bid - 14016) * 256 + threadIdx.x; }
  else                  { s = asp;  d = aspb;  j = (bid - 14040) * 256 + threadIdx.x; }
  const float4* sp = (const float4*)s;
  float4 a = sp[2*j], b = sp[2*j+1];
  uint4 o;
  o.x = (unsigned)f2bf(a.x) | ((unsigned)f2bf(a.y) << 16);
  o.y = (unsigned)f2bf(a.z) | ((unsigned)f2bf(a.w) << 16);
  o.z = (unsigned)f2bf(b.x) | ((unsigned)f2bf(b.y) << 16);
  o.w = (unsigned)f2bf(b.z) | ((unsigned)f2bf(b.w) << 16);
  ((uint4*)d)[j] = o;
}

// ------- fallback-path prep kernels (GEMM-first ordering when ws is small) -------
__global__ __launch_bounds__(256) void k_conv_bf16(const float* __restrict__ src,
                                                   unsigned short* __restrict__ dst, int n8){
  int i = blockIdx.x * 256 + threadIdx.x;
  if (i >= n8) return;
  const float4* s = (const float4*)src;
  float4 a = s[2*i], b = s[2*i+1];
  uint4 o;
  o.x = (unsigned)f2bf(a.x) | ((unsigned)f2bf(a.y) << 16);
  o.y = (unsigned)f2bf(a.z) | ((unsigned)f2bf(a.w) << 16);
  o.z = (unsigned)f2bf(b.x) | ((unsigned)f2bf(b.y) << 16);
  o.w = (unsigned)f2bf(b.z) | ((unsigned)f2bf(b.w) << 16);
  ((uint4*)dst)[i] = o;
}

__global__ __launch_bounds__(256) void k_conv4(const float* __restrict__ s0, unsigned short* __restrict__ d0, int c0,
                                               const float* __restrict__ s1, unsigned short* __restrict__ d1, int c1,
                                               const float* __restrict__ s2, unsigned short* __restrict__ d2, int c2,
                                               const float* __restrict__ s3, unsigned short* __restrict__ d3, int c3){
  int i = blockIdx.x * 256 + threadIdx.x;
  const float* s; unsigned short* d; int j;
  if (i < c0) { s = s0; d = d0; j = i; }
  else if (i < c0 + c1) { s = s1; d = d1; j = i - c0; }
  else if (i < c0 + c1 + c2) { s = s2; d = d2; j = i - c0 - c1; }
  else if (i < c0 + c1 + c2 + c3) { s = s3; d = d3; j = i - c0 - c1 - c2; }
  else return;
  const float4* sp = (const float4*)s;
  float4 a = sp[2*j], b = sp[2*j+1];
  uint4 o;
  o.x = (unsigned)f2bf(a.x) | ((unsigned)f2bf(a.y) << 16);
  o.y = (unsigned)f2bf(a.z) | ((unsigned)f2bf(a.w) << 16);
  o.z = (unsigned)f2bf(b.x) | ((unsigned)f2bf(b.y) << 16);
  o.w = (unsigned)f2bf(b.z) | ((unsigned)f2bf(b.w) << 16);
  ((uint4*)d)[j] = o;
}

__global__ __launch_bounds__(256) void k_transpose_ws(const float* __restrict__ src,
                                                      unsigned short* __restrict__ dst){
  __shared__ float tile[32][33];
  int bx = blockIdx.x * 32, by = blockIdx.y * 32;
  int tx = threadIdx.x % 32, ty = threadIdx.x / 32;
  for (int j = ty; j < 32; j += 8) tile[j][tx] = src[(size_t)(by + j) * Hdim + bx + tx];
  __syncthreads();
  for (int j = ty; j < 32; j += 8) dst[(size_t)(bx + j) * Hdim + by + tx] = f2bf(tile[tx][j]);
}

__global__ __launch_bounds__(256) void k_transpose4(const float* __restrict__ s0, unsigned short* __restrict__ d0,
                                                    const float* __restrict__ s1, unsigned short* __restrict__ d1,
                                                    const float* __restrict__ s2, unsigned short* __restrict__ d2,
                                                    const float* __restrict__ s3, unsigned short* __restrict__ d3){
  const float* src; unsigned short* dst;
  switch (blockIdx.z) {
    case 0: src = s0; dst = d0; break;
    case 1: src = s1; dst = d1; break;
    case 2: src = s2; dst = d2; break;
    default: src = s3; dst = d3; break;
  }
  __shared__ float tile[32][33];
  int bx = blockIdx.x * 32, by = blockIdx.y * 32;
  int tx = threadIdx.x % 32, ty = threadIdx.x / 32;
  for (int j = ty; j < 32; j += 8) tile[j][tx] = src[(size_t)(by + j) * Hdim + bx + tx];
  __syncthreads();
  for (int j = ty; j < 32; j += 8) dst[(size_t)(bx + j) * Hdim + by + tx] = f2bf(tile[tx][j]);
}

// ---------------- Se = SEb @ ws : bf16 MFMA, global_load_lds staging (verified 56us) ----------------
__global__ __launch_bounds__(256) void k_gemm_se(const unsigned short* __restrict__ A,
                                                 const unsigned short* __restrict__ Bt,
                                                 unsigned short* __restrict__ C){
  __shared__ unsigned short As[128 * 64];
  __shared__ unsigned short Bs[128 * 64];
  const int t = threadIdx.x;
  const int lane = t & 63;
  const int w = t >> 6, wr = w >> 1, wc = w & 1;
  int bid = blockIdx.x;
  int swz = (bid & 7) * 192 + (bid >> 3);
  const int m0 = (swz / 6) * 128, n0 = (swz % 6) * 128;

  f32x4 acc[4][4];
  #pragma unroll
  for (int m = 0; m < 4; m++)
    #pragma unroll
    for (int n = 0; n < 4; n++) acc[m][n] = (f32x4){0.f, 0.f, 0.f, 0.f};

  for (int k0 = 0; k0 < Hdim; k0 += 64) {
    #pragma unroll
    for (int i = 0; i < 4; i++) {
      int L = t * 16 + i * 4096;
      int row = L >> 7;
      int offp = L & 127;
      int goff = offp ^ ((row & 7) << 4);
      int wub = __builtin_amdgcn_readfirstlane((t & 192) * 16 + i * 4096);
      gload16((const char*)A  + ((size_t)(m0 + row) * Hdim + k0) * 2 + goff, (char*)As + wub);
      gload16((const char*)Bt + ((size_t)(n0 + row) * Hdim + k0) * 2 + goff, (char*)Bs + wub);
    }
    __syncthreads();
    #pragma unroll
    for (int kk = 0; kk < 2; kk++) {
      s16x8 af[4], bfr[4];
      #pragma unroll
      for (int m = 0; m < 4; m++) {
        int row = wr * 64 + m * 16 + (lane & 15);
        int sw = (row & 7) << 4;
        int kb = kk * 64 + (lane >> 4) * 8;
        s16x4 lo = *(const s16x4*)((const char*)As + row * 128 + (kb ^ sw));
        s16x4 hi = *(const s16x4*)((const char*)As + row * 128 + ((kb + 32) ^ sw));
        af[m] = __builtin_shufflevector(lo, hi, 0, 1, 2, 3, 4, 5, 6, 7);
      }
      #pragma unroll
      for (int n = 0; n < 4; n++) {
        int row = wc * 64 + n * 16 + (lane & 15);
        int sw = (row & 7) << 4;
        int kb = kk * 64 + (lane >> 4) * 8;
        s16x4 lo = *(const s16x4*)((const char*)Bs + row * 128 + (kb ^ sw));
        s16x4 hi = *(const s16x4*)((const char*)Bs + row * 128 + ((kb + 32) ^ sw));
        bfr[n] = __builtin_shufflevector(lo, hi, 0, 1, 2, 3, 4, 5, 6, 7);
      }
      #pragma unroll
      for (int m = 0; m < 4; m++)
        #pragma unroll
        for (int n = 0; n < 4; n++)
          acc[m][n] = __builtin_amdgcn_mfma_f32_16x16x32_bf16(af[m], bfr[n], acc[m][n], 0, 0, 0);
    }
    __syncthreads();
  }
  #pragma unroll
  for (int m = 0; m < 4; m++) {
    int rowb = m0 + wr * 64 + m * 16 + (lane >> 4) * 4;
    #pragma unroll
    for (int n = 0; n < 4; n++) {
      int col = n0 + wc * 64 + n * 16 + (lane & 15);
      #pragma unroll
      for (int r = 0; r < 4; r++)
        C[(size_t)(rowb + r) * Hdim + col] = f2bf(acc[m][n][r]);
    }
  }
}

// ---------------- shared small-GEMM device bodies (LDS passed in) ----------------
__device__ __forceinline__ void smallM_body(const unsigned short* __restrict__ A,
                                            const unsigned short* __restrict__ Bt,
                                            float* __restrict__ C, unsigned short* __restrict__ Cb,
                                            char* ldsbuf, int n0){
  unsigned short* As = (unsigned short*)ldsbuf;            // 64x64
  unsigned short* Bs = (unsigned short*)(ldsbuf + 8192);   // 128x64
  const int t = threadIdx.x, lane = t & 63, w = t >> 6;
  f32x4 acc[4][2];
  #pragma unroll
  for (int m = 0; m < 4; m++)
    #pragma unroll
    for (int n = 0; n < 2; n++) acc[m][n] = (f32x4){0.f, 0.f, 0.f, 0.f};

  for (int k0 = 0; k0 < Hdim; k0 += 64) {
    #pragma unroll
    for (int i = 0; i < 2; i++) {
      int L = t * 16 + i * 4096, row = L >> 7, off = L & 127;
      *(uint4*)((char*)As + row * 128 + (off ^ ((row & 7) << 4))) =
        *(const uint4*)((const char*)A + ((size_t)row * Hdim + k0) * 2 + off);
    }
    #pragma unroll
    for (int i = 0; i < 4; i++) {
      int L = t * 16 + i * 4096, row = L >> 7, off = L & 127;
      *(uint4*)((char*)Bs + row * 128 + (off ^ ((row & 7) << 4))) =
        *(const uint4*)((const char*)Bt + ((size_t)(n0 + row) * Hdim + k0) * 2 + off);
    }
    __syncthreads();
    #pragma unroll
    for (int kk = 0; kk < 2; kk++) {
      s16x8 af[4], bfr[2];
      int kb = kk * 64 + (lane >> 4) * 8;
      #pragma unroll
      for (int m = 0; m < 4; m++) {
        int row = m * 16 + (lane & 15);
        int sw = (row & 7) << 4;
        s16x4 lo = *(const s16x4*)((const char*)As + row * 128 + (kb ^ sw));
        s16x4 hi = *(const s16x4*)((const char*)As + row * 128 + ((kb + 32) ^ sw));
        af[m] = __builtin_shufflevector(lo, hi, 0, 1, 2, 3, 4, 5, 6, 7);
      }
      #pragma unroll
      for (int n = 0; n < 2; n++) {
        int row = w * 32 + n * 16 + (lane & 15);
        int sw = (row & 7) << 4;
        s16x4 lo = *(const s16x4*)((const char*)Bs + row * 128 + (kb ^ sw));
        s16x4 hi = *(const s16x4*)((const char*)Bs + row * 128 + ((kb + 32) ^ sw));
        bfr[n] = __builtin_shufflevector(lo, hi, 0, 1, 2, 3, 4, 5, 6, 7);
      }
      #pragma unroll
      for (int m = 0; m < 4; m++)
        #pragma unroll
        for (int n = 0; n < 2; n++)
          acc[m][n] = __builtin_amdgcn_mfma_f32_16x16x32_bf16(af[m], bfr[n], acc[m][n], 0, 0, 0);
    }
    __syncthreads();
  }
  #pragma unroll
  for (int m = 0; m < 4; m++) {
    int rowb = m * 16 + (lane >> 4) * 4;
    #pragma unroll
    for (int n = 0; n < 2; n++) {
      int col = n0 + w * 32 + n * 16 + (lane & 15);
      #pragma unroll
      for (int r = 0; r < 4; r++) {
        float v = acc[m][n][r];
        C[(size_t)(rowb + r) * Hdim + col] = v;
        if (Cb) Cb[(size_t)(rowb + r) * Hdim + col] = f2bf(v);
      }
    }
  }
}

__device__ __forceinline__ void vpart_body(const unsigned short* __restrict__ A1,
                                           const unsigned short* __restrict__ B1t,
                                           const unsigned short* __restrict__ A2,
                                           const unsigned short* __restrict__ B2t,
                                           float* __restrict__ Vp,
                                           char* ldsbuf, int n0, int kc){
  unsigned short* As = (unsigned short*)ldsbuf;
  unsigned short* Bs = (unsigned short*)(ldsbuf + 8192);
  const int t = threadIdx.x, lane = t & 63, w = t >> 6;
  f32x4 acc[4][2];
  #pragma unroll
  for (int m = 0; m < 4; m++)
    #pragma unroll
    for (int n = 0; n < 2; n++) acc[m][n] = (f32x4){0.f, 0.f, 0.f, 0.f};

  #pragma unroll
  for (int gi = 0; gi < 4; gi++) {
    int g = kc * 4 + gi;
    const unsigned short* A  = (g < 12) ? A1 : A2;
    const unsigned short* Bt = (g < 12) ? B1t : B2t;
    int k0 = (g % 12) * 64;
    #pragma unroll
    for (int i = 0; i < 2; i++) {
      int L = t * 16 + i * 4096, row = L >> 7, off = L & 127;
      *(uint4*)((char*)As + row * 128 + (off ^ ((row & 7) << 4))) =
        *(const uint4*)((const char*)A + ((size_t)row * Hdim + k0) * 2 + off);
    }
    #pragma unroll
    for (int i = 0; i < 4; i++) {
      int L = t * 16 + i * 4096, row = L >> 7, off = L & 127;
      *(uint4*)((char*)Bs + row * 128 + (off ^ ((row & 7) << 4))) =
        *(const uint4*)((const char*)Bt + ((size_t)(n0 + row) * Hdim + k0) * 2 + off);
    }
    __syncthreads();
    #pragma unroll
    for (int kk = 0; kk < 2; kk++) {
      s16x8 af[4], bfr[2];
      int kb = kk * 64 + (lane >> 4) * 8;
      #pragma unroll
      for (int m = 0; m < 4; m++) {
        int row = m * 16 + (lane & 15);
        int sw = (row & 7) << 4;
        s16x4 lo = *(const s16x4*)((const char*)As + row * 128 + (kb ^ sw));
        s16x4 hi = *(const s16x4*)((const char*)As + row * 128 + ((kb + 32) ^ sw));
        af[m] = __builtin_shufflevector(lo, hi, 0, 1, 2, 3, 4, 5, 6, 7);
      }
      #pragma unroll
      for (int n = 0; n < 2; n++) {
        int row = w * 32 + n * 16 + (lane & 15);
        int sw = (row & 7) << 4;
        s16x4 lo = *(const s16x4*)((const char*)Bs + row * 128 + (kb ^ sw));
        s16x4 hi = *(const s16x4*)((const char*)Bs + row * 128 + ((kb + 32) ^ sw));
        bfr[n] = __builtin_shufflevector(lo, hi, 0, 1, 2, 3, 4, 5, 6, 7);
      }
      #pragma unroll
      for (int m = 0; m < 4; m++)
        #pragma unroll
        for (int n = 0; n < 2; n++)
          acc[m][n] = __builtin_amdgcn_mfma_f32_16x16x32_bf16(af[m], bfr[n], acc[m][n], 0, 0, 0);
    }
    __syncthreads();
  }
  float* outp = Vp + (size_t)kc * (Bdim * Hdim);
  #pragma unroll
  for (int m = 0; m < 4; m++) {
    int rowb = m * 16 + (lane >> 4) * 4;
    #pragma unroll
    for (int n = 0; n < 2; n++) {
      int col = n0 + w * 32 + n * 16 + (lane & 15);
      #pragma unroll
      for (int r = 0; r < 4; r++)
        outp[(size_t)(rowb + r) * Hdim + col] = acc[m][n][r];
    }
  }
}

// gates K-chunk GEMM body: out[kc][64][G3] partial over K range [kc*384, kc*384+384)
__device__ __forceinline__ void gates_body(const unsigned short* __restrict__ A,
                                           const unsigned short* __restrict__ Bt,
                                           float* __restrict__ outp,
                                           char* ldsbuf, int n0, int kc){
  unsigned short* As = (unsigned short*)ldsbuf;
  unsigned short* Bs = (unsigned short*)(ldsbuf + 8192);
  const int t = threadIdx.x, lane = t & 63, w = t >> 6;
  f32x4 acc[4][2];
  #pragma unroll
  for (int m = 0; m < 4; m++)
    #pragma unroll
    for (int n = 0; n < 2; n++) acc[m][n] = (f32x4){0.f, 0.f, 0.f, 0.f};

  for (int it = 0; it < 6; it++) {
    int k0 = kc * 384 + it * 64;
    #pragma unroll
    for (int i = 0; i < 2; i++) {
      int L = t * 16 + i * 4096, row = L >> 7, off = L & 127;
      *(uint4*)((char*)As + row * 128 + (off ^ ((row & 7) << 4))) =
        *(const uint4*)((const char*)A + ((size_t)row * Hdim + k0) * 2 + off);
    }
    #pragma unroll
    for (int i = 0; i < 4; i++) {
      int L = t * 16 + i * 4096, row = L >> 7, off = L & 127;
      *(uint4*)((char*)Bs + row * 128 + (off ^ ((row & 7) << 4))) =
        *(const uint4*)((const char*)Bt + ((size_t)(n0 + row) * Hdim + k0) * 2 + off);
    }
    __syncthreads();
    #pragma unroll
    for (int kk = 0; kk < 2; kk++) {
      s16x8 af[4], bfr[2];
      int kb = kk * 64 + (lane >> 4) * 8;
      #pragma unroll
      for (int m = 0; m < 4; m++) {
        int row = m * 16 + (lane & 15);
        int sw = (row & 7) << 4;
        s16x4 lo = *(const s16x4*)((const char*)As + row * 128 + (kb ^ sw));
        s16x4 hi = *(const s16x4*)((const char*)As + row * 128 + ((kb + 32) ^ sw));
        af[m] = __builtin_shufflevector(lo, hi, 0, 1, 2, 3, 4, 5, 6, 7);
      }
      #pragma unroll
      for (int n = 0; n < 2; n++) {
        int row = w * 32 + n * 16 + (lane & 15);
        int sw = (row & 7) << 4;
        s16x4 lo = *(const s16x4*)((const char*)Bs + row * 128 + (kb ^ sw));
        s16x4 hi = *(const s16x4*)((const char*)Bs + row * 128 + ((kb + 32) ^ sw));
        bfr[n] = __builtin_shufflevector(lo, hi, 0, 1, 2, 3, 4, 5, 6, 7);
      }
      #pragma unroll
      for (int m = 0; m < 4; m++)
        #pragma unroll
        for (int n = 0; n < 2; n++)
          acc[m][n] = __builtin_amdgcn_mfma_f32_16x16x32_bf16(af[m], bfr[n], acc[m][n], 0, 0, 0);
    }
    __syncthreads();
  }
  #pragma unroll
  for (int m = 0; m < 4; m++) {
    int rowb = m * 16 + (lane >> 4) * 4;
    #pragma unroll
    for (int n = 0; n < 2; n++) {
      int col = n0 + w * 32 + n * 16 + (lane & 15);
      #pragma unroll
      for (int r = 0; r < 4; r++)
        outp[(size_t)(rowb + r) * G3 + col] = acc[m][n][r];
    }
  }
}

// per-layer V partials: grid (6, 6)
__global__ __launch_bounds__(256) void k_vpart(const unsigned short* __restrict__ A1,
                                               const unsigned short* __restrict__ B1t,
                                               const unsigned short* __restrict__ A2,
                                               const unsigned short* __restrict__ B2t,
                                               float* __restrict__ Vp){
  __shared__ char lds[24576];
  vpart_body(A1, B1t, A2, B2t, Vp, lds, blockIdx.x * 128, blockIdx.y);
}

// init: grid (6, 7): y<6 -> V0 partials; y==6 -> h0 = srb@whsT
__global__ __launch_bounds__(256) void k_init2(const unsigned short* __restrict__ srb,
                                               const unsigned short* __restrict__ whsT,
                                               float* __restrict__ hA, unsigned short* __restrict__ hbA,
                                               const unsigned short* __restrict__ wd1T,
                                               const unsigned short* __restrict__ aspb,
                                               const unsigned short* __restrict__ waT,
                                               float* __restrict__ Vp){
  __shared__ char lds[24576];
  if (blockIdx.y == 6) smallM_body(srb, whsT, hA, hbA, lds, blockIdx.x * 128);
  else                 vpart_body(srb, wd1T, aspb, waT, Vp, lds, blockIdx.x * 128, blockIdx.y);
}

// ---------------- fused: scores (x<32) + gh gate-GEMM (x==32) ----------------
// scores[b,s] = sum_k tanh(Se[b,s,k] + V[b,k]) * w[k] (V = sum of 6 partials)
// gh2[kc] = hb @ w_hhb-slice (independent of scores; same readiness)
__global__ __launch_bounds__(256) void k_scores_gh(const unsigned short* __restrict__ Seb,
                                                   const float* __restrict__ Vp,
                                                   const float* __restrict__ wv,
                                                   float* __restrict__ scores,
                                                   const unsigned short* __restrict__ hb,
                                                   const unsigned short* __restrict__ w_hhb,
                                                   float* __restrict__ gh2){
  __shared__ char lds[24576];
  if (blockIdx.x == 32) {
    int idx = blockIdx.y;
    if (idx >= 36) return;
    int kc = idx / 18, nb = idx % 18;
    gates_body(hb, w_hhb, gh2 + (size_t)kc * (Bdim * G3), lds, nb * 128, kc);
    return;
  }
  int b = blockIdx.y;
  int s_base = blockIdx.x * 16;
  int t = threadIdx.x, lane = t & 63, w = t >> 6;
  f32x4 v0 = {0,0,0,0}, v1 = {0,0,0,0}, v2 = {0,0,0,0};
  #pragma unroll
  for (int kc = 0; kc < 6; kc++) {
    const float* Vb = Vp + ((size_t)kc * Bdim + b) * Hdim;
    v0 += *(const f32x4*)(Vb + lane * 8);
    v1 += *(const f32x4*)(Vb + lane * 8 + 4);
    v2 += *(const f32x4*)(Vb + 512 + lane * 4);
  }
  f32x4 w0 = *(const f32x4*)(wv + lane * 8);
  f32x4 w1 = *(const f32x4*)(wv + lane * 8 + 4);
  f32x4 w2 = *(const f32x4*)(wv + 512 + lane * 4);
  #pragma unroll
  for (int si = 0; si < 4; si++) {
    int s = s_base + w * 4 + si;
    const unsigned short* rp = Seb + ((size_t)b * Sdim + s) * Hdim;
    ushort4 p0 = *(const ushort4*)(rp + lane * 8);
    ushort4 p1 = *(const ushort4*)(rp + lane * 8 + 4);
    ushort4 p2 = *(const ushort4*)(rp + 512 + lane * 4);
    float acc;
    acc  = fast_tanh(bf2f(p0.x) + v0[0]) * w0[0];
    acc += fast_tanh(bf2f(p0.y) + v0[1]) * w0[1];
    acc += fast_tanh(bf2f(p0.z) + v0[2]) * w0[2];
    acc += fast_tanh(bf2f(p0.w) + v0[3]) * w0[3];
    acc += fast_tanh(bf2f(p1.x) + v1[0]) * w1[0];
    acc += fast_tanh(bf2f(p1.y) + v1[1]) * w1[1];
    acc += fast_tanh(bf2f(p1.z) + v1[2]) * w1[2];
    acc += fast_tanh(bf2f(p1.w) + v1[3]) * w1[3];
    acc += fast_tanh(bf2f(p2.x) + v2[0]) * w2[0];
    acc += fast_tanh(bf2f(p2.y) + v2[1]) * w2[1];
    acc += fast_tanh(bf2f(p2.z) + v2[2]) * w2[2];
    acc += fast_tanh(bf2f(p2.w) + v2[3]) * w2[3];
    #pragma unroll
    for (int o = 32; o; o >>= 1) acc += __shfl_xor(acc, o);
    if (lane == 0) scores[(size_t)b * Sdim + s] = acc;
  }
}

// ---------------- fused softmax + masked pooling partials + last-block reduce -> atb ----------------
__global__ __launch_bounds__(192) void k_at_sm_bf16(const unsigned short* __restrict__ SEb,
                                                    const float* __restrict__ scores,
                                                    const float* __restrict__ mask,
                                                    float* __restrict__ at_part,
                                                    unsigned short* __restrict__ atb,
                                                    int* __restrict__ cnt){
  int sc = blockIdx.x, b = blockIdx.y;
  int t = threadIdx.x, lane = t & 63, w = t >> 6;
  __shared__ float sbuf[512];
  __shared__ float mbuf[512];
  __shared__ float red[3], red2[3];
  __shared__ float msh[64];
  __shared__ float half0[96 * 8];
  __shared__ int lastflag;
  float lmax = -1e30f;
  #pragma unroll
  for (int j = 0; j < 3; j++) {
    int idx = t + 192 * j;
    if (idx < 512) {
      float v = scores[(size_t)b * Sdim + idx];
      float mk = mask[(size_t)b * Sdim + idx];
      sbuf[idx] = v; mbuf[idx] = mk;
      lmax = fmaxf(lmax, v);
    }
  }
  #pragma unroll
  for (int o = 32; o; o >>= 1) lmax = fmaxf(lmax, __shfl_xor(lmax, o));
  if (lane == 0) red[w] = lmax;
  __syncthreads();
  float mx = fmaxf(fmaxf(red[0], red[1]), red[2]);
  float le = 0.f, lm = 0.f;
  #pragma unroll
  for (int j = 0; j < 3; j++) {
    int idx = t + 192 * j;
    if (idx < 512) {
      float e = __expf(sbuf[idx] - mx);
      le += e; lm += mbuf[idx];
      sbuf[idx] = e * mbuf[idx];
    }
  }
  #pragma unroll
  for (int o = 32; o; o >>= 1) { le += __shfl_xor(le, o); lm += __shfl_xor(lm, o); }
  __syncthreads();
  if (lane == 0) { red[w] = le; red2[w] = lm; }
  __syncthreads();
  float inv = 1.f / ((red[0] + red[1] + red[2]) * (red2[0] + red2[1] + red2[2]));
  if (t < 64) msh[t] = sbuf[sc * 64 + t] * inv;
  __syncthreads();
  int hseg = t % 96, sh = t / 96;
  const unsigned short* base = SEb + ((size_t)b * Sdim + sc * 64 + sh * 32) * Hdim + hseg * 8;
  float acc[8] = {0, 0, 0, 0, 0, 0, 0, 0};
  for (int s = 0; s < 32; s++) {
    float m = msh[sh * 32 + s];
    ushort4 a = *(const ushort4*)(base + (size_t)s * Hdim);
    ushort4 c = *(const ushort4*)(base + (size_t)s * Hdim + 4);
    acc[0] += m * bf2f(a.x); acc[1] += m * bf2f(a.y); acc[2] += m * bf2f(a.z); acc[3] += m * bf2f(a.w);
    acc[4] += m * bf2f(c.x); acc[5] += m * bf2f(c.y); acc[6] += m * bf2f(c.z); acc[7] += m * bf2f(c.w);
  }
  if (sh == 0) {
    #pragma unroll
    for (int j = 0; j < 8; j++) half0[hseg * 8 + j] = acc[j];
  }
  __syncthreads();
  if (sh == 1) {
    float* op = at_part + ((size_t)sc * Bdim + b) * Hdim + hseg * 8;
    #pragma unroll
    for (int j = 0; j < 8; j++) op[j] = acc[j] + half0[hseg * 8 + j];
  }
  // publish partial; 8th arriver for this b reduces -> atb (fixed p order, deterministic)
  __threadfence();
  __syncthreads();
  if (t == 0) lastflag = atomicAdd(&cnt[b], 1);
  __syncthreads();
  if (lastflag == 7) {
    __threadfence();
    for (int col = t; col < Hdim; col += 192) {
      float s = 0.f;
      #pragma unroll
      for (int p = 0; p < 8; p++) s += at_part[((size_t)p * Bdim + b) * Hdim + col];
      atb[(size_t)b * Hdim + col] = f2bf(s);
    }
  }
}

__global__ __launch_bounds__(192) void k_at_sm_f32(const float* __restrict__ SE,
                                                   const float* __restrict__ scores,
                                                   const float* __restrict__ mask,
                                                   float* __restrict__ at_part,
                                                   unsigned short* __restrict__ atb,
                                                   int* __restrict__ cnt){
  int sc = blockIdx.x, b = blockIdx.y;
  int t = threadIdx.x, lane = t & 63, w = t >> 6;
  __shared__ float sbuf[512];
  __shared__ float mbuf[512];
  __shared__ float red[3], red2[3];
  __shared__ float msh[64];
  __shared__ float half0[96 * 8];
  __shared__ int lastflag;
  float lmax = -1e30f;
  #pragma unroll
  for (int j = 0; j < 3; j++) {
    int idx = t + 192 * j;
    if (idx < 512) {
      float v = scores[(size_t)b * Sdim + idx];
      float mk = mask[(size_t)b * Sdim + idx];
      sbuf[idx] = v; mbuf[idx] = mk;
      lmax = fmaxf(lmax, v);
    }
  }
  #pragma unroll
  for (int o = 32; o; o >>= 1) lmax = fmaxf(lmax, __shfl_xor(lmax, o));
  if (lane == 0) red[w] = lmax;
  __syncthreads();
  float mx = fmaxf(fmaxf(red[0], red[1]), red[2]);
  float le = 0.f, lm = 0.f;
  #pragma unroll
  for (int j = 0; j < 3; j++) {
    int idx = t + 192 * j;
    if (idx < 512) {
      float e = __expf(sbuf[idx] - mx);
      le += e; lm += mbuf[idx];
      sbuf[idx] = e * mbuf[idx];
    }
  }
  #pragma unroll
  for (int o = 32; o; o >>= 1) { le += __shfl_xor(le, o); lm += __shfl_xor(lm, o); }
  __syncthreads();
  if (lane == 0) { red[w] = le; red2[w] = lm; }
  __syncthreads();
  float inv = 1.f / ((red[0] + red[1] + red[2]) * (red2[0] + red2[1] + red2[2]));
  if (t < 64) msh[t] = sbuf[sc * 64 + t] * inv;
  __syncthreads();
  int hseg = t % 96, sh = t / 96;
  const float* base = SE + ((size_t)b * Sdim + sc * 64 + sh * 32) * Hdim + hseg * 8;
  float acc[8] = {0, 0, 0, 0, 0, 0, 0, 0};
  for (int s = 0; s < 32; s++) {
    float m = msh[sh * 32 + s];
    float4 a = *(const float4*)(base + (size_t)s * Hdim);
    float4 c = *(const float4*)(base + (size_t)s * Hdim + 4);
    acc[0] += m * a.x; acc[1] += m * a.y; acc[2] += m * a.z; acc[3] += m * a.w;
    acc[4] += m * c.x; acc[5] += m * c.y; acc[6] += m * c.z; acc[7] += m * c.w;
  }
  if (sh == 0) {
    #pragma unroll
    for (int j = 0; j < 8; j++) half0[hseg * 8 + j] = acc[j];
  }
  __syncthreads();
  if (sh == 1) {
    float* op = at_part + ((size_t)sc * Bdim + b) * Hdim + hseg * 8;
    #pragma unroll
    for (int j = 0; j < 8; j++) op[j] = acc[j] + half0[hseg * 8 + j];
  }
  __threadfence();
  __syncthreads();
  if (t == 0) lastflag = atomicAdd(&cnt[b], 1);
  __syncthreads();
  if (lastflag == 7) {
    __threadfence();
    for (int col = t; col < Hdim; col += 192) {
      float s = 0.f;
      #pragma unroll
      for (int p = 0; p < 8; p++) s += at_part[((size_t)p * Bdim + b) * Hdim + col];
      atb[(size_t)b * Hdim + col] = f2bf(s);
    }
  }
}

// ---------------- gi gate-GEMM, K-split: grid (18, kc=2) ----------------
__global__ __launch_bounds__(256) void k_gates_gi(const unsigned short* __restrict__ atb,
                                                  const unsigned short* __restrict__ w_ihb,
                                                  float* __restrict__ gi2){
  __shared__ char lds[24576];
  int kc = blockIdx.y;
  gates_body(atb, w_ihb, gi2 + (size_t)kc * (Bdim * G3), lds, blockIdx.x * 128, kc);
}

// ---------------- GRU elementwise (sums 2 K-partials) ----------------
__global__ __launch_bounds__(256) void k_gru_elem2(const float* __restrict__ gi2,
                                                   const float* __restrict__ gh2,
                                                   const float* __restrict__ h,
                                                   float* __restrict__ hout,
                                                   unsigned short* __restrict__ hbout){
  int i = blockIdx.x * 256 + threadIdx.x;
  int b = i / Hdim, g = i % Hdim;
  const size_t P = (size_t)Bdim * G3;
  const float* gia = gi2 + (size_t)b * G3;
  const float* gha = gh2 + (size_t)b * G3;
  float ir = gia[g] + gia[P + g];
  float iz = gia[Hdim + g] + gia[P + Hdim + g];
  float in_ = gia[2 * Hdim + g] + gia[P + 2 * Hdim + g];
  float hr = gha[g] + gha[P + g];
  float hz = gha[Hdim + g] + gha[P + Hdim + g];
  float hn = gha[2 * Hdim + g] + gha[P + 2 * Hdim + g];
  float r = fast_sigmoid(ir + hr);
  float z = fast_sigmoid(iz + hz);
  float n = fast_tanh(in_ + r * hn);
  float ho = (1.f - z) * n + z * h[i];
  hout[i] = ho;
  hbout[i] = f2bf(ho);
}

// ---------------- host ----------------
extern "C" void kernel_launch(void* const* d_in, const int* in_sizes, int n_in,
                              void* d_out, int out_size, void* d_ws, size_t ws_size,
                              hipStream_t stream) {
  const float* sr   = (const float*)d_in[0];
  const float* mask = (const float*)d_in[1];
  const float* asp  = (const float*)d_in[2];
  const float* SE   = (const float*)d_in[3];
  const float* ws_  = (const float*)d_in[4];
  const float* wa   = (const float*)d_in[5];
  const float* wv   = (const float*)d_in[6];
  const float* whs  = (const float*)d_in[7];
  const float* wd1  = (const float*)d_in[8];
  const float* wd   = (const float*)d_in[9];
  const float* w_ih = (const float*)d_in[10];
  const float* w_hh = (const float*)d_in[11];
  float* out = (float*)d_out;

  char* p = (char*)d_ws;
  size_t offA = 0;
  auto A_ = [&](size_t b) -> char* { char* r = p + offA; offA += b; return r; };
  unsigned short* Seb  = (unsigned short*)A_(50331648);  // Se bf16, alive all layers
  unsigned short* wsbT = (unsigned short*)A_(1179648);   // ws^T bf16
  int* cnt = (int*)A_(1024);                             // 3 layers x 64 batch counters (never aliased)
  unsigned short* SEb  = (unsigned short*)A_(50331648);  // SE bf16 (GEMM A; pool input if kept)

  const size_t othersBytes = 18100224;
  bool keepSEb = (offA + othersBytes) <= ws_size;
  char* q = keepSEb ? (p + offA) : (char*)SEb;  // fallback: alias over SEb (written post-GEMM only)
  size_t o2 = 0;
  auto B_ = [&](size_t b) -> char* { char* r = q + o2; o2 += b; return r; };
  unsigned short* w_ihb = (unsigned short*)B_(3538944);
  unsigned short* w_hhb = (unsigned short*)B_(3538944);
  unsigned short* wd1T  = (unsigned short*)B_(1179648);
  unsigned short* wdT   = (unsigned short*)B_(1179648);
  unsigned short* waT   = (unsigned short*)B_(1179648);
  unsigned short* whsT  = (unsigned short*)B_(1179648);
  unsigned short* srb   = (unsigned short*)B_(98304);
  unsigned short* aspb  = (unsigned short*)B_(98304);
  float* Vp      = (float*)B_(1179648);   // [6][64][768]
  float* scores  = (float*)B_(131072);
  float* at_part = (float*)B_(1572864);   // [8][64][768]
  unsigned short* atb = (unsigned short*)B_(98304);
  float* gi2     = (float*)B_(1179648);   // [2][64][2304]
  float* gh2     = (float*)B_(1179648);
  float* hA      = (float*)B_(196608);
  float* hB      = (float*)B_(196608);
  unsigned short* hbA = (unsigned short*)B_(98304);
  unsigned short* hbB = (unsigned short*)B_(98304);
  if (!keepSEb && (offA > ws_size)) return;  // need >= ~102MB

  hipMemsetAsync(cnt, 0, 3 * 64 * sizeof(int), stream);

  // ---- prep ----
  if (keepSEb) {
    k_prep<<<dim3(16944), dim3(256), 0, stream>>>(SE, SEb, ws_, wsbT, wd1, wd1T, wd, wdT,
                                                  wa, waT, whs, whsT, w_ih, w_ihb, w_hh, w_hhb,
                                                  sr, srb, asp, aspb);
    k_gemm_se<<<dim3(1536), dim3(256), 0, stream>>>(SEb, wsbT, Seb);
  } else {
    k_conv_bf16<<<dim3(12288), dim3(256), 0, stream>>>(SE, SEb, 3145728);
    k_transpose_ws<<<dim3(24, 24), dim3(256), 0, stream>>>(ws_, wsbT);
    k_gemm_se<<<dim3(1536), dim3(256), 0, stream>>>(SEb, wsbT, Seb);
    k_transpose4<<<dim3(24, 24, 4), dim3(256), 0, stream>>>(wd1, wd1T, wd, wdT, wa, waT, whs, whsT);
    k_conv4<<<dim3(1776), dim3(256), 0, stream>>>(w_ih, w_ihb, 221184, w_hh, w_hhb, 221184,
                                                  sr, srb, 6144, asp, aspb, 6144);
  }
  k_init2<<<dim3(6, 7), dim3(256), 0, stream>>>(srb, whsT, hA, hbA, wd1T, aspb, waT, Vp);

  const float* hcur = hA;
  const unsigned short* hbcur = hbA;
  for (int tl = 0; tl < 3; ++tl) {
    if (tl > 0)
      k_vpart<<<dim3(6, 6), dim3(256), 0, stream>>>(hbcur, wdT, aspb, waT, Vp);
    k_scores_gh<<<dim3(33, 64), dim3(256), 0, stream>>>(Seb, Vp, wv, scores, hbcur, w_hhb, gh2);
    if (keepSEb)
      k_at_sm_bf16<<<dim3(8, 64), dim3(192), 0, stream>>>(SEb, scores, mask, at_part, atb, cnt + tl * 64);
    else
      k_at_sm_f32<<<dim3(8, 64), dim3(192), 0, stream>>>(SE, scores, mask, at_part, atb, cnt + tl * 64);
    k_gates_gi<<<dim3(18, 2), dim3(256), 0, stream>>>(atb, w_ihb, gi2);
    float* hout = (tl == 2) ? out : ((hcur == hA) ? hB : hA);
    unsigned short* hbout = (hbcur == hbA) ? hbB : hbA;
    k_gru_elem2<<<dim3(192), dim3(256), 0, stream>>>(gi2, gh2, hcur, hout, hbout);
    hcur = hout;
    hbcur = hbout;
  }
}

// Round 10
// 235.997 us; speedup vs baseline: 1.7001x; 1.7001x over previous
//
#include <hip/hip_runtime.h>
#include <hip/hip_bf16.h>
#include <stdint.h>

#define Bdim 64
#define Sdim 512
#define Hdim 768
#define G3   2304

typedef float f32x4 __attribute__((ext_vector_type(4)));
typedef short s16x8 __attribute__((ext_vector_type(8)));
typedef short s16x4 __attribute__((ext_vector_type(4)));

__device__ __forceinline__ float bf2f(unsigned short u){
  union { unsigned int i; float f; } c; c.i = ((unsigned int)u) << 16; return c.f;
}
__device__ __forceinline__ float bflo(unsigned int x){
  union { unsigned int i; float f; } c; c.i = x << 16; return c.f;
}
__device__ __forceinline__ float bfhi(unsigned int x){
  union { unsigned int i; float f; } c; c.i = x & 0xffff0000u; return c.f;
}
__device__ __forceinline__ unsigned short f2bf(float f){
  union { float f; unsigned int i; } c; c.f = f;
  unsigned int x = c.i;
  return (unsigned short)((x + 0x7fffu + ((x >> 16) & 1u)) >> 16);
}
__device__ __forceinline__ float fast_tanh(float x){
  float e = __expf(2.f * x);
  return 1.f - 2.f / (e + 1.f);
}
__device__ __forceinline__ float fast_sigmoid(float x){
  return 1.f / (1.f + __expf(-x));
}
// async global->LDS, 16B per lane; lds base must be wave-uniform
__device__ __forceinline__ void gload16(const void* g, void* l){
  __builtin_amdgcn_global_load_lds((const __attribute__((address_space(1))) void*)g,
                                   (__attribute__((address_space(3))) void*)l, 16, 0, 0);
}

// ---------------- merged prep: 5 transposes (64x64 tiles) + 5 bf16 casts ----------------
// blocks [0,720): transpose 768x768 f32->bf16^T (ws,wd1,wd,wa,whs; 144 each, 64x64 tiles)
// blocks [720,14784): f32->bf16 casts (SE 12288, w_ih 864, w_hh 864, sr 24, asp 24)
__global__ __launch_bounds__(256) void k_prep(const float* __restrict__ SE, unsigned short* __restrict__ SEb,
                                              const float* __restrict__ ws_, unsigned short* __restrict__ wsbT,
                                              const float* __restrict__ wd1, unsigned short* __restrict__ wd1T,
                                              const float* __restrict__ wd,  unsigned short* __restrict__ wdT,
                                              const float* __restrict__ wa,  unsigned short* __restrict__ waT,
                                              const float* __restrict__ whs, unsigned short* __restrict__ whsT,
                                              const float* __restrict__ w_ih, unsigned short* __restrict__ w_ihb,
                                              const float* __restrict__ w_hh, unsigned short* __restrict__ w_hhb,
                                              const float* __restrict__ sr,  unsigned short* __restrict__ srb,
                                              const float* __restrict__ asp, unsigned short* __restrict__ aspb){
  __shared__ float tile[64][65];
  int bid = blockIdx.x;
  if (bid < 720) {
    int which = bid / 144, r = bid % 144;
    const float* src; unsigned short* dst;
    switch (which) {
      case 0: src = ws_; dst = wsbT; break;
      case 1: src = wd1; dst = wd1T; break;
      case 2: src = wd;  dst = wdT;  break;
      case 3: src = wa;  dst = waT;  break;
      default: src = whs; dst = whsT; break;
    }
    int bx = (r % 12) * 64, by = (r / 12) * 64;
    int tx = threadIdx.x % 64, ty = threadIdx.x / 64;
    #pragma unroll
    for (int j = ty; j < 64; j += 4) tile[j][tx] = src[(size_t)(by + j) * Hdim + bx + tx];
    __syncthreads();
    #pragma unroll
    for (int j = ty; j < 64; j += 4) dst[(size_t)(bx + j) * Hdim + by + tx] = f2bf(tile[tx][j]);
    return;
  }
  bid -= 720;
  const float* s; unsigned short* d; int j;
  if      (bid < 12288) { s = SE;   d = SEb;   j = bid * 256 + threadIdx.x; }
  else if (bid < 13152) { s = w_ih; d = w_ihb; j = (bid - 12288) * 256 + threadIdx.x; }
  else if (bid < 14016) { s = w_hh; d = w_hhb; j = (bid - 13152) * 256 + threadIdx.x; }
  else if (bid < 14040) { s = sr;   d = srb;   j = (bid - 14016) * 256 + threadIdx.x; }
  else                  { s = asp;  d = aspb;  j = (bid - 14040) * 256 + threadIdx.x; }
  const float4* sp = (const float4*)s;
  float4 a = sp[2*j], b = sp[2*j+1];
  uint4 o;
  o.x = (unsigned)f2bf(a.x) | ((unsigned)f2bf(a.y) << 16);
  o.y = (unsigned)f2bf(a.z) | ((unsigned)f2bf(a.w) << 16);
  o.z = (unsigned)f2bf(b.x) | ((unsigned)f2bf(b.y) << 16);
  o.w = (unsigned)f2bf(b.z) | ((unsigned)f2bf(b.w) << 16);
  ((uint4*)d)[j] = o;
}

// ------- fallback-path prep kernels (GEMM-first ordering when ws is small) -------
__global__ __launch_bounds__(256) void k_conv_bf16(const float* __restrict__ src,
                                                   unsigned short* __restrict__ dst, int n8){
  int i = blockIdx.x * 256 + threadIdx.x;
  if (i >= n8) return;
  const float4* s = (const float4*)src;
  float4 a = s[2*i], b = s[2*i+1];
  uint4 o;
  o.x = (unsigned)f2bf(a.x) | ((unsigned)f2bf(a.y) << 16);
  o.y = (unsigned)f2bf(a.z) | ((unsigned)f2bf(a.w) << 16);
  o.z = (unsigned)f2bf(b.x) | ((unsigned)f2bf(b.y) << 16);
  o.w = (unsigned)f2bf(b.z) | ((unsigned)f2bf(b.w) << 16);
  ((uint4*)dst)[i] = o;
}

__global__ __launch_bounds__(256) void k_conv4(const float* __restrict__ s0, unsigned short* __restrict__ d0, int c0,
                                               const float* __restrict__ s1, unsigned short* __restrict__ d1, int c1,
                                               const float* __restrict__ s2, unsigned short* __restrict__ d2, int c2,
                                               const float* __restrict__ s3, unsigned short* __restrict__ d3, int c3){
  int i = blockIdx.x * 256 + threadIdx.x;
  const float* s; unsigned short* d; int j;
  if (i < c0) { s = s0; d = d0; j = i; }
  else if (i < c0 + c1) { s = s1; d = d1; j = i - c0; }
  else if (i < c0 + c1 + c2) { s = s2; d = d2; j = i - c0 - c1; }
  else if (i < c0 + c1 + c2 + c3) { s = s3; d = d3; j = i - c0 - c1 - c2; }
  else return;
  const float4* sp = (const float4*)s;
  float4 a = sp[2*j], b = sp[2*j+1];
  uint4 o;
  o.x = (unsigned)f2bf(a.x) | ((unsigned)f2bf(a.y) << 16);
  o.y = (unsigned)f2bf(a.z) | ((unsigned)f2bf(a.w) << 16);
  o.z = (unsigned)f2bf(b.x) | ((unsigned)f2bf(b.y) << 16);
  o.w = (unsigned)f2bf(b.z) | ((unsigned)f2bf(b.w) << 16);
  ((uint4*)d)[j] = o;
}

__global__ __launch_bounds__(256) void k_transpose_ws(const float* __restrict__ src,
                                                      unsigned short* __restrict__ dst){
  __shared__ float tile[32][33];
  int bx = blockIdx.x * 32, by = blockIdx.y * 32;
  int tx = threadIdx.x % 32, ty = threadIdx.x / 32;
  for (int j = ty; j < 32; j += 8) tile[j][tx] = src[(size_t)(by + j) * Hdim + bx + tx];
  __syncthreads();
  for (int j = ty; j < 32; j += 8) dst[(size_t)(bx + j) * Hdim + by + tx] = f2bf(tile[tx][j]);
}

__global__ __launch_bounds__(256) void k_transpose4(const float* __restrict__ s0, unsigned short* __restrict__ d0,
                                                    const float* __restrict__ s1, unsigned short* __restrict__ d1,
                                                    const float* __restrict__ s2, unsigned short* __restrict__ d2,
                                                    const float* __restrict__ s3, unsigned short* __restrict__ d3){
  const float* src; unsigned short* dst;
  switch (blockIdx.z) {
    case 0: src = s0; dst = d0; break;
    case 1: src = s1; dst = d1; break;
    case 2: src = s2; dst = d2; break;
    default: src = s3; dst = d3; break;
  }
  __shared__ float tile[32][33];
  int bx = blockIdx.x * 32, by = blockIdx.y * 32;
  int tx = threadIdx.x % 32, ty = threadIdx.x / 32;
  for (int j = ty; j < 32; j += 8) tile[j][tx] = src[(size_t)(by + j) * Hdim + bx + tx];
  __syncthreads();
  for (int j = ty; j < 32; j += 8) dst[(size_t)(bx + j) * Hdim + by + tx] = f2bf(tile[tx][j]);
}

// ---------------- Se = SEb @ ws : bf16 MFMA, global_load_lds staging (verified 56us) ----------------
__global__ __launch_bounds__(256) void k_gemm_se(const unsigned short* __restrict__ A,
                                                 const unsigned short* __restrict__ Bt,
                                                 unsigned short* __restrict__ C){
  __shared__ unsigned short As[128 * 64];
  __shared__ unsigned short Bs[128 * 64];
  const int t = threadIdx.x;
  const int lane = t & 63;
  const int w = t >> 6, wr = w >> 1, wc = w & 1;
  int bid = blockIdx.x;
  int swz = (bid & 7) * 192 + (bid >> 3);
  const int m0 = (swz / 6) * 128, n0 = (swz % 6) * 128;

  f32x4 acc[4][4];
  #pragma unroll
  for (int m = 0; m < 4; m++)
    #pragma unroll
    for (int n = 0; n < 4; n++) acc[m][n] = (f32x4){0.f, 0.f, 0.f, 0.f};

  for (int k0 = 0; k0 < Hdim; k0 += 64) {
    #pragma unroll
    for (int i = 0; i < 4; i++) {
      int L = t * 16 + i * 4096;
      int row = L >> 7;
      int offp = L & 127;
      int goff = offp ^ ((row & 7) << 4);
      int wub = __builtin_amdgcn_readfirstlane((t & 192) * 16 + i * 4096);
      gload16((const char*)A  + ((size_t)(m0 + row) * Hdim + k0) * 2 + goff, (char*)As + wub);
      gload16((const char*)Bt + ((size_t)(n0 + row) * Hdim + k0) * 2 + goff, (char*)Bs + wub);
    }
    __syncthreads();
    #pragma unroll
    for (int kk = 0; kk < 2; kk++) {
      s16x8 af[4], bfr[4];
      #pragma unroll
      for (int m = 0; m < 4; m++) {
        int row = wr * 64 + m * 16 + (lane & 15);
        int sw = (row & 7) << 4;
        int kb = kk * 64 + (lane >> 4) * 8;
        s16x4 lo = *(const s16x4*)((const char*)As + row * 128 + (kb ^ sw));
        s16x4 hi = *(const s16x4*)((const char*)As + row * 128 + ((kb + 32) ^ sw));
        af[m] = __builtin_shufflevector(lo, hi, 0, 1, 2, 3, 4, 5, 6, 7);
      }
      #pragma unroll
      for (int n = 0; n < 4; n++) {
        int row = wc * 64 + n * 16 + (lane & 15);
        int sw = (row & 7) << 4;
        int kb = kk * 64 + (lane >> 4) * 8;
        s16x4 lo = *(const s16x4*)((const char*)Bs + row * 128 + (kb ^ sw));
        s16x4 hi = *(const s16x4*)((const char*)Bs + row * 128 + ((kb + 32) ^ sw));
        bfr[n] = __builtin_shufflevector(lo, hi, 0, 1, 2, 3, 4, 5, 6, 7);
      }
      #pragma unroll
      for (int m = 0; m < 4; m++)
        #pragma unroll
        for (int n = 0; n < 4; n++)
          acc[m][n] = __builtin_amdgcn_mfma_f32_16x16x32_bf16(af[m], bfr[n], acc[m][n], 0, 0, 0);
    }
    __syncthreads();
  }
  #pragma unroll
  for (int m = 0; m < 4; m++) {
    int rowb = m0 + wr * 64 + m * 16 + (lane >> 4) * 4;
    #pragma unroll
    for (int n = 0; n < 4; n++) {
      int col = n0 + wc * 64 + n * 16 + (lane & 15);
      #pragma unroll
      for (int r = 0; r < 4; r++)
        C[(size_t)(rowb + r) * Hdim + col] = f2bf(acc[m][n][r]);
    }
  }
}

// ---------------- shared small-GEMM device bodies (LDS passed in) ----------------
__device__ __forceinline__ void smallM_body(const unsigned short* __restrict__ A,
                                            const unsigned short* __restrict__ Bt,
                                            float* __restrict__ C, unsigned short* __restrict__ Cb,
                                            char* ldsbuf, int n0){
  unsigned short* As = (unsigned short*)ldsbuf;            // 64x64
  unsigned short* Bs = (unsigned short*)(ldsbuf + 8192);   // 128x64
  const int t = threadIdx.x, lane = t & 63, w = t >> 6;
  f32x4 acc[4][2];
  #pragma unroll
  for (int m = 0; m < 4; m++)
    #pragma unroll
    for (int n = 0; n < 2; n++) acc[m][n] = (f32x4){0.f, 0.f, 0.f, 0.f};

  for (int k0 = 0; k0 < Hdim; k0 += 64) {
    #pragma unroll
    for (int i = 0; i < 2; i++) {
      int L = t * 16 + i * 4096, row = L >> 7, off = L & 127;
      *(uint4*)((char*)As + row * 128 + (off ^ ((row & 7) << 4))) =
        *(const uint4*)((const char*)A + ((size_t)row * Hdim + k0) * 2 + off);
    }
    #pragma unroll
    for (int i = 0; i < 4; i++) {
      int L = t * 16 + i * 4096, row = L >> 7, off = L & 127;
      *(uint4*)((char*)Bs + row * 128 + (off ^ ((row & 7) << 4))) =
        *(const uint4*)((const char*)Bt + ((size_t)(n0 + row) * Hdim + k0) * 2 + off);
    }
    __syncthreads();
    #pragma unroll
    for (int kk = 0; kk < 2; kk++) {
      s16x8 af[4], bfr[2];
      int kb = kk * 64 + (lane >> 4) * 8;
      #pragma unroll
      for (int m = 0; m < 4; m++) {
        int row = m * 16 + (lane & 15);
        int sw = (row & 7) << 4;
        s16x4 lo = *(const s16x4*)((const char*)As + row * 128 + (kb ^ sw));
        s16x4 hi = *(const s16x4*)((const char*)As + row * 128 + ((kb + 32) ^ sw));
        af[m] = __builtin_shufflevector(lo, hi, 0, 1, 2, 3, 4, 5, 6, 7);
      }
      #pragma unroll
      for (int n = 0; n < 2; n++) {
        int row = w * 32 + n * 16 + (lane & 15);
        int sw = (row & 7) << 4;
        s16x4 lo = *(const s16x4*)((const char*)Bs + row * 128 + (kb ^ sw));
        s16x4 hi = *(const s16x4*)((const char*)Bs + row * 128 + ((kb + 32) ^ sw));
        bfr[n] = __builtin_shufflevector(lo, hi, 0, 1, 2, 3, 4, 5, 6, 7);
      }
      #pragma unroll
      for (int m = 0; m < 4; m++)
        #pragma unroll
        for (int n = 0; n < 2; n++)
          acc[m][n] = __builtin_amdgcn_mfma_f32_16x16x32_bf16(af[m], bfr[n], acc[m][n], 0, 0, 0);
    }
    __syncthreads();
  }
  #pragma unroll
  for (int m = 0; m < 4; m++) {
    int rowb = m * 16 + (lane >> 4) * 4;
    #pragma unroll
    for (int n = 0; n < 2; n++) {
      int col = n0 + w * 32 + n * 16 + (lane & 15);
      #pragma unroll
      for (int r = 0; r < 4; r++) {
        float v = acc[m][n][r];
        C[(size_t)(rowb + r) * Hdim + col] = v;
        if (Cb) Cb[(size_t)(rowb + r) * Hdim + col] = f2bf(v);
      }
    }
  }
}

__device__ __forceinline__ void vpart_body(const unsigned short* __restrict__ A1,
                                           const unsigned short* __restrict__ B1t,
                                           const unsigned short* __restrict__ A2,
                                           const unsigned short* __restrict__ B2t,
                                           float* __restrict__ Vp,
                                           char* ldsbuf, int n0, int kc){
  unsigned short* As = (unsigned short*)ldsbuf;
  unsigned short* Bs = (unsigned short*)(ldsbuf + 8192);
  const int t = threadIdx.x, lane = t & 63, w = t >> 6;
  f32x4 acc[4][2];
  #pragma unroll
  for (int m = 0; m < 4; m++)
    #pragma unroll
    for (int n = 0; n < 2; n++) acc[m][n] = (f32x4){0.f, 0.f, 0.f, 0.f};

  #pragma unroll
  for (int gi = 0; gi < 4; gi++) {
    int g = kc * 4 + gi;
    const unsigned short* A  = (g < 12) ? A1 : A2;
    const unsigned short* Bt = (g < 12) ? B1t : B2t;
    int k0 = (g % 12) * 64;
    #pragma unroll
    for (int i = 0; i < 2; i++) {
      int L = t * 16 + i * 4096, row = L >> 7, off = L & 127;
      *(uint4*)((char*)As + row * 128 + (off ^ ((row & 7) << 4))) =
        *(const uint4*)((const char*)A + ((size_t)row * Hdim + k0) * 2 + off);
    }
    #pragma unroll
    for (int i = 0; i < 4; i++) {
      int L = t * 16 + i * 4096, row = L >> 7, off = L & 127;
      *(uint4*)((char*)Bs + row * 128 + (off ^ ((row & 7) << 4))) =
        *(const uint4*)((const char*)Bt + ((size_t)(n0 + row) * Hdim + k0) * 2 + off);
    }
    __syncthreads();
    #pragma unroll
    for (int kk = 0; kk < 2; kk++) {
      s16x8 af[4], bfr[2];
      int kb = kk * 64 + (lane >> 4) * 8;
      #pragma unroll
      for (int m = 0; m < 4; m++) {
        int row = m * 16 + (lane & 15);
        int sw = (row & 7) << 4;
        s16x4 lo = *(const s16x4*)((const char*)As + row * 128 + (kb ^ sw));
        s16x4 hi = *(const s16x4*)((const char*)As + row * 128 + ((kb + 32) ^ sw));
        af[m] = __builtin_shufflevector(lo, hi, 0, 1, 2, 3, 4, 5, 6, 7);
      }
      #pragma unroll
      for (int n = 0; n < 2; n++) {
        int row = w * 32 + n * 16 + (lane & 15);
        int sw = (row & 7) << 4;
        s16x4 lo = *(const s16x4*)((const char*)Bs + row * 128 + (kb ^ sw));
        s16x4 hi = *(const s16x4*)((const char*)Bs + row * 128 + ((kb + 32) ^ sw));
        bfr[n] = __builtin_shufflevector(lo, hi, 0, 1, 2, 3, 4, 5, 6, 7);
      }
      #pragma unroll
      for (int m = 0; m < 4; m++)
        #pragma unroll
        for (int n = 0; n < 2; n++)
          acc[m][n] = __builtin_amdgcn_mfma_f32_16x16x32_bf16(af[m], bfr[n], acc[m][n], 0, 0, 0);
    }
    __syncthreads();
  }
  float* outp = Vp + (size_t)kc * (Bdim * Hdim);
  #pragma unroll
  for (int m = 0; m < 4; m++) {
    int rowb = m * 16 + (lane >> 4) * 4;
    #pragma unroll
    for (int n = 0; n < 2; n++) {
      int col = n0 + w * 32 + n * 16 + (lane & 15);
      #pragma unroll
      for (int r = 0; r < 4; r++)
        outp[(size_t)(rowb + r) * Hdim + col] = acc[m][n][r];
    }
  }
}

// per-layer V partials: grid (6, 6)
__global__ __launch_bounds__(256) void k_vpart(const unsigned short* __restrict__ A1,
                                               const unsigned short* __restrict__ B1t,
                                               const unsigned short* __restrict__ A2,
                                               const unsigned short* __restrict__ B2t,
                                               float* __restrict__ Vp){
  __shared__ char lds[24576];
  vpart_body(A1, B1t, A2, B2t, Vp, lds, blockIdx.x * 128, blockIdx.y);
}

// init: grid (6, 7): y<6 -> V0 partials; y==6 -> h0 = srb@whsT
__global__ __launch_bounds__(256) void k_init2(const unsigned short* __restrict__ srb,
                                               const unsigned short* __restrict__ whsT,
                                               float* __restrict__ hA, unsigned short* __restrict__ hbA,
                                               const unsigned short* __restrict__ wd1T,
                                               const unsigned short* __restrict__ aspb,
                                               const unsigned short* __restrict__ waT,
                                               float* __restrict__ Vp){
  __shared__ char lds[24576];
  if (blockIdx.y == 6) smallM_body(srb, whsT, hA, hbA, lds, blockIdx.x * 128);
  else                 vpart_body(srb, wd1T, aspb, waT, Vp, lds, blockIdx.x * 128, blockIdx.y);
}

// ---------------- scores[b,s] = sum_k tanh(Se[b,s,k] + V[b,k]) * w[k] (V = sum of 6 partials) ----------------
__global__ __launch_bounds__(256) void k_scores(const unsigned short* __restrict__ Seb,
                                                const float* __restrict__ Vp,
                                                const float* __restrict__ wv,
                                                float* __restrict__ scores){
  int b = blockIdx.y;
  int s_base = blockIdx.x * 16;
  int t = threadIdx.x, lane = t & 63, w = t >> 6;
  f32x4 v0 = {0,0,0,0}, v1 = {0,0,0,0}, v2 = {0,0,0,0};
  #pragma unroll
  for (int kc = 0; kc < 6; kc++) {
    const float* Vb = Vp + ((size_t)kc * Bdim + b) * Hdim;
    v0 += *(const f32x4*)(Vb + lane * 8);
    v1 += *(const f32x4*)(Vb + lane * 8 + 4);
    v2 += *(const f32x4*)(Vb + 512 + lane * 4);
  }
  f32x4 w0 = *(const f32x4*)(wv + lane * 8);
  f32x4 w1 = *(const f32x4*)(wv + lane * 8 + 4);
  f32x4 w2 = *(const f32x4*)(wv + 512 + lane * 4);
  #pragma unroll
  for (int si = 0; si < 4; si++) {
    int s = s_base + w * 4 + si;
    const unsigned short* rp = Seb + ((size_t)b * Sdim + s) * Hdim;
    ushort4 p0 = *(const ushort4*)(rp + lane * 8);
    ushort4 p1 = *(const ushort4*)(rp + lane * 8 + 4);
    ushort4 p2 = *(const ushort4*)(rp + 512 + lane * 4);
    float acc;
    acc  = fast_tanh(bf2f(p0.x) + v0[0]) * w0[0];
    acc += fast_tanh(bf2f(p0.y) + v0[1]) * w0[1];
    acc += fast_tanh(bf2f(p0.z) + v0[2]) * w0[2];
    acc += fast_tanh(bf2f(p0.w) + v0[3]) * w0[3];
    acc += fast_tanh(bf2f(p1.x) + v1[0]) * w1[0];
    acc += fast_tanh(bf2f(p1.y) + v1[1]) * w1[1];
    acc += fast_tanh(bf2f(p1.z) + v1[2]) * w1[2];
    acc += fast_tanh(bf2f(p1.w) + v1[3]) * w1[3];
    acc += fast_tanh(bf2f(p2.x) + v2[0]) * w2[0];
    acc += fast_tanh(bf2f(p2.y) + v2[1]) * w2[1];
    acc += fast_tanh(bf2f(p2.z) + v2[2]) * w2[2];
    acc += fast_tanh(bf2f(p2.w) + v2[3]) * w2[3];
    #pragma unroll
    for (int o = 32; o; o >>= 1) acc += __shfl_xor(acc, o);
    if (lane == 0) scores[(size_t)b * Sdim + s] = acc;
  }
}

// ---------------- fused softmax + masked pooling partials (bf16 SE), 16 s-chunks ----------------
// grid (16, 64), 192 threads; each block pools 32 s-rows (2x16 split)
__global__ __launch_bounds__(192) void k_at_sm_bf16(const unsigned short* __restrict__ SEb,
                                                    const float* __restrict__ scores,
                                                    const float* __restrict__ mask,
                                                    float* __restrict__ at_part){
  int sc = blockIdx.x, b = blockIdx.y;
  int t = threadIdx.x, lane = t & 63, w = t >> 6;
  __shared__ float sbuf[512];
  __shared__ float mbuf[512];
  __shared__ float red[3], red2[3];
  __shared__ float msh[32];
  __shared__ float half0[96 * 8];
  float lmax = -1e30f;
  #pragma unroll
  for (int j = 0; j < 3; j++) {
    int idx = t + 192 * j;
    if (idx < 512) {
      float v = scores[(size_t)b * Sdim + idx];
      float mk = mask[(size_t)b * Sdim + idx];
      sbuf[idx] = v; mbuf[idx] = mk;
      lmax = fmaxf(lmax, v);
    }
  }
  #pragma unroll
  for (int o = 32; o; o >>= 1) lmax = fmaxf(lmax, __shfl_xor(lmax, o));
  if (lane == 0) red[w] = lmax;
  __syncthreads();
  float mx = fmaxf(fmaxf(red[0], red[1]), red[2]);
  float le = 0.f, lm = 0.f;
  #pragma unroll
  for (int j = 0; j < 3; j++) {
    int idx = t + 192 * j;
    if (idx < 512) {
      float e = __expf(sbuf[idx] - mx);
      le += e; lm += mbuf[idx];
      sbuf[idx] = e * mbuf[idx];
    }
  }
  #pragma unroll
  for (int o = 32; o; o >>= 1) { le += __shfl_xor(le, o); lm += __shfl_xor(lm, o); }
  __syncthreads();
  if (lane == 0) { red[w] = le; red2[w] = lm; }
  __syncthreads();
  float inv = 1.f / ((red[0] + red[1] + red[2]) * (red2[0] + red2[1] + red2[2]));
  if (t < 32) msh[t] = sbuf[sc * 32 + t] * inv;
  __syncthreads();
  // pooling: 32 rows split 2x16; per-thread 8 cols via one uint4 (16B) load
  int hseg = t % 96, sh = t / 96;
  const unsigned short* base = SEb + ((size_t)b * Sdim + sc * 32 + sh * 16) * Hdim + hseg * 8;
  float acc[8] = {0, 0, 0, 0, 0, 0, 0, 0};
  #pragma unroll
  for (int s = 0; s < 16; s++) {
    float m = msh[sh * 16 + s];
    uint4 v = *(const uint4*)(base + (size_t)s * Hdim);
    acc[0] += m * bflo(v.x); acc[1] += m * bfhi(v.x);
    acc[2] += m * bflo(v.y); acc[3] += m * bfhi(v.y);
    acc[4] += m * bflo(v.z); acc[5] += m * bfhi(v.z);
    acc[6] += m * bflo(v.w); acc[7] += m * bfhi(v.w);
  }
  if (sh == 0) {
    #pragma unroll
    for (int j = 0; j < 8; j++) half0[hseg * 8 + j] = acc[j];
  }
  __syncthreads();
  if (sh == 1) {
    float* op = at_part + ((size_t)sc * Bdim + b) * Hdim + hseg * 8;
    #pragma unroll
    for (int j = 0; j < 8; j++) op[j] = acc[j] + half0[hseg * 8 + j];
  }
}

// ---------------- f32 fallback, same 16-chunk structure ----------------
__global__ __launch_bounds__(192) void k_at_sm_f32(const float* __restrict__ SE,
                                                   const float* __restrict__ scores,
                                                   const float* __restrict__ mask,
                                                   float* __restrict__ at_part){
  int sc = blockIdx.x, b = blockIdx.y;
  int t = threadIdx.x, lane = t & 63, w = t >> 6;
  __shared__ float sbuf[512];
  __shared__ float mbuf[512];
  __shared__ float red[3], red2[3];
  __shared__ float msh[32];
  __shared__ float half0[96 * 8];
  float lmax = -1e30f;
  #pragma unroll
  for (int j = 0; j < 3; j++) {
    int idx = t + 192 * j;
    if (idx < 512) {
      float v = scores[(size_t)b * Sdim + idx];
      float mk = mask[(size_t)b * Sdim + idx];
      sbuf[idx] = v; mbuf[idx] = mk;
      lmax = fmaxf(lmax, v);
    }
  }
  #pragma unroll
  for (int o = 32; o; o >>= 1) lmax = fmaxf(lmax, __shfl_xor(lmax, o));
  if (lane == 0) red[w] = lmax;
  __syncthreads();
  float mx = fmaxf(fmaxf(red[0], red[1]), red[2]);
  float le = 0.f, lm = 0.f;
  #pragma unroll
  for (int j = 0; j < 3; j++) {
    int idx = t + 192 * j;
    if (idx < 512) {
      float e = __expf(sbuf[idx] - mx);
      le += e; lm += mbuf[idx];
      sbuf[idx] = e * mbuf[idx];
    }
  }
  #pragma unroll
  for (int o = 32; o; o >>= 1) { le += __shfl_xor(le, o); lm += __shfl_xor(lm, o); }
  __syncthreads();
  if (lane == 0) { red[w] = le; red2[w] = lm; }
  __syncthreads();
  float inv = 1.f / ((red[0] + red[1] + red[2]) * (red2[0] + red2[1] + red2[2]));
  if (t < 32) msh[t] = sbuf[sc * 32 + t] * inv;
  __syncthreads();
  int hseg = t % 96, sh = t / 96;
  const float* base = SE + ((size_t)b * Sdim + sc * 32 + sh * 16) * Hdim + hseg * 8;
  float acc[8] = {0, 0, 0, 0, 0, 0, 0, 0};
  #pragma unroll
  for (int s = 0; s < 16; s++) {
    float m = msh[sh * 16 + s];
    float4 a = *(const float4*)(base + (size_t)s * Hdim);
    float4 c = *(const float4*)(base + (size_t)s * Hdim + 4);
    acc[0] += m * a.x; acc[1] += m * a.y; acc[2] += m * a.z; acc[3] += m * a.w;
    acc[4] += m * c.x; acc[5] += m * c.y; acc[6] += m * c.z; acc[7] += m * c.w;
  }
  if (sh == 0) {
    #pragma unroll
    for (int j = 0; j < 8; j++) half0[hseg * 8 + j] = acc[j];
  }
  __syncthreads();
  if (sh == 1) {
    float* op = at_part + ((size_t)sc * Bdim + b) * Hdim + hseg * 8;
    #pragma unroll
    for (int j = 0; j < 8; j++) op[j] = acc[j] + half0[hseg * 8 + j];
  }
}

// ---------------- at reduce: sum 16 partials -> bf16 ----------------
__global__ __launch_bounds__(256) void k_at_reduce(const float* __restrict__ at_part,
                                                   unsigned short* __restrict__ atb){
  int i = blockIdx.x * 256 + threadIdx.x;
  float s = 0.f;
  #pragma unroll
  for (int p = 0; p < 16; p++) s += at_part[(size_t)p * (Bdim * Hdim) + i];
  atb[i] = f2bf(s);
}

// ---------------- GRU gate GEMMs, K-split: grid (18, z=2, kc=2) (verified) ----------------
__global__ __launch_bounds__(256) void k_gates2(const unsigned short* __restrict__ atb,
                                                const unsigned short* __restrict__ hb,
                                                const unsigned short* __restrict__ w_ihb,
                                                const unsigned short* __restrict__ w_hhb,
                                                float* __restrict__ gi2,
                                                float* __restrict__ gh2){
  __shared__ unsigned short As[64 * 64];
  __shared__ unsigned short Bs[128 * 64];
  const int t = threadIdx.x, lane = t & 63, w = t >> 6;
  const int n0 = blockIdx.x * 128;
  const int z = blockIdx.y, kc = blockIdx.z;
  const unsigned short* A  = z ? hb : atb;
  const unsigned short* Bt = z ? w_hhb : w_ihb;
  float* outp = (z ? gh2 : gi2) + (size_t)kc * (Bdim * G3);
  f32x4 acc[4][2];
  #pragma unroll
  for (int m = 0; m < 4; m++)
    #pragma unroll
    for (int n = 0; n < 2; n++) acc[m][n] = (f32x4){0.f, 0.f, 0.f, 0.f};

  for (int it = 0; it < 6; it++) {
    int k0 = kc * 384 + it * 64;
    #pragma unroll
    for (int i = 0; i < 2; i++) {
      int L = t * 16 + i * 4096, row = L >> 7, off = L & 127;
      *(uint4*)((char*)As + row * 128 + (off ^ ((row & 7) << 4))) =
        *(const uint4*)((const char*)A + ((size_t)row * Hdim + k0) * 2 + off);
    }
    #pragma unroll
    for (int i = 0; i < 4; i++) {
      int L = t * 16 + i * 4096, row = L >> 7, off = L & 127;
      *(uint4*)((char*)Bs + row * 128 + (off ^ ((row & 7) << 4))) =
        *(const uint4*)((const char*)Bt + ((size_t)(n0 + row) * Hdim + k0) * 2 + off);
    }
    __syncthreads();
    #pragma unroll
    for (int kk = 0; kk < 2; kk++) {
      s16x8 af[4], bfr[2];
      int kb = kk * 64 + (lane >> 4) * 8;
      #pragma unroll
      for (int m = 0; m < 4; m++) {
        int row = m * 16 + (lane & 15);
        int sw = (row & 7) << 4;
        s16x4 lo = *(const s16x4*)((const char*)As + row * 128 + (kb ^ sw));
        s16x4 hi = *(const s16x4*)((const char*)As + row * 128 + ((kb + 32) ^ sw));
        af[m] = __builtin_shufflevector(lo, hi, 0, 1, 2, 3, 4, 5, 6, 7);
      }
      #pragma unroll
      for (int n = 0; n < 2; n++) {
        int row = w * 32 + n * 16 + (lane & 15);
        int sw = (row & 7) << 4;
        s16x4 lo = *(const s16x4*)((const char*)Bs + row * 128 + (kb ^ sw));
        s16x4 hi = *(const s16x4*)((const char*)Bs + row * 128 + ((kb + 32) ^ sw));
        bfr[n] = __builtin_shufflevector(lo, hi, 0, 1, 2, 3, 4, 5, 6, 7);
      }
      #pragma unroll
      for (int m = 0; m < 4; m++)
        #pragma unroll
        for (int n = 0; n < 2; n++)
          acc[m][n] = __builtin_amdgcn_mfma_f32_16x16x32_bf16(af[m], bfr[n], acc[m][n], 0, 0, 0);
    }
    __syncthreads();
  }
  #pragma unroll
  for (int m = 0; m < 4; m++) {
    int rowb = m * 16 + (lane >> 4) * 4;
    #pragma unroll
    for (int n = 0; n < 2; n++) {
      int col = n0 + w * 32 + n * 16 + (lane & 15);
      #pragma unroll
      for (int r = 0; r < 4; r++)
        outp[(size_t)(rowb + r) * G3 + col] = acc[m][n][r];
    }
  }
}

// ---------------- GRU elementwise (sums 2 K-partials) ----------------
__global__ __launch_bounds__(256) void k_gru_elem2(const float* __restrict__ gi2,
                                                   const float* __restrict__ gh2,
                                                   const float* __restrict__ h,
                                                   float* __restrict__ hout,
                                                   unsigned short* __restrict__ hbout){
  int i = blockIdx.x * 256 + threadIdx.x;
  int b = i / Hdim, g = i % Hdim;
  const size_t P = (size_t)Bdim * G3;
  const float* gia = gi2 + (size_t)b * G3;
  const float* gha = gh2 + (size_t)b * G3;
  float ir = gia[g] + gia[P + g];
  float iz = gia[Hdim + g] + gia[P + Hdim + g];
  float in_ = gia[2 * Hdim + g] + gia[P + 2 * Hdim + g];
  float hr = gha[g] + gha[P + g];
  float hz = gha[Hdim + g] + gha[P + Hdim + g];
  float hn = gha[2 * Hdim + g] + gha[P + 2 * Hdim + g];
  float r = fast_sigmoid(ir + hr);
  float z = fast_sigmoid(iz + hz);
  float n = fast_tanh(in_ + r * hn);
  float ho = (1.f - z) * n + z * h[i];
  hout[i] = ho;
  hbout[i] = f2bf(ho);
}

// ---------------- host ----------------
extern "C" void kernel_launch(void* const* d_in, const int* in_sizes, int n_in,
                              void* d_out, int out_size, void* d_ws, size_t ws_size,
                              hipStream_t stream) {
  const float* sr   = (const float*)d_in[0];
  const float* mask = (const float*)d_in[1];
  const float* asp  = (const float*)d_in[2];
  const float* SE   = (const float*)d_in[3];
  const float* ws_  = (const float*)d_in[4];
  const float* wa   = (const float*)d_in[5];
  const float* wv   = (const float*)d_in[6];
  const float* whs  = (const float*)d_in[7];
  const float* wd1  = (const float*)d_in[8];
  const float* wd   = (const float*)d_in[9];
  const float* w_ih = (const float*)d_in[10];
  const float* w_hh = (const float*)d_in[11];
  float* out = (float*)d_out;

  char* p = (char*)d_ws;
  size_t offA = 0;
  auto A_ = [&](size_t b) -> char* { char* r = p + offA; offA += b; return r; };
  unsigned short* Seb  = (unsigned short*)A_(50331648);  // Se bf16, alive all layers
  unsigned short* wsbT = (unsigned short*)A_(1179648);   // ws^T bf16
  unsigned short* SEb  = (unsigned short*)A_(50331648);  // SE bf16 (GEMM A; pool input if kept)

  const size_t othersBytes = 19673088;
  bool keepSEb = (offA + othersBytes) <= ws_size;
  char* q = keepSEb ? (p + offA) : (char*)SEb;  // fallback: alias over SEb (written post-GEMM only)
  size_t o2 = 0;
  auto B_ = [&](size_t b) -> char* { char* r = q + o2; o2 += b; return r; };
  unsigned short* w_ihb = (unsigned short*)B_(3538944);
  unsigned short* w_hhb = (unsigned short*)B_(3538944);
  unsigned short* wd1T  = (unsigned short*)B_(1179648);
  unsigned short* wdT   = (unsigned short*)B_(1179648);
  unsigned short* waT   = (unsigned short*)B_(1179648);
  unsigned short* whsT  = (unsigned short*)B_(1179648);
  unsigned short* srb   = (unsigned short*)B_(98304);
  unsigned short* aspb  = (unsigned short*)B_(98304);
  float* Vp      = (float*)B_(1179648);   // [6][64][768]
  float* scores  = (float*)B_(131072);
  float* at_part = (float*)B_(3145728);   // [16][64][768]
  unsigned short* atb = (unsigned short*)B_(98304);
  float* gi2     = (float*)B_(1179648);   // [2][64][2304]
  float* gh2     = (float*)B_(1179648);
  float* hA      = (float*)B_(196608);
  float* hB      = (float*)B_(196608);
  unsigned short* hbA = (unsigned short*)B_(98304);
  unsigned short* hbB = (unsigned short*)B_(98304);
  if (!keepSEb && (offA > ws_size)) return;  // need >= ~102MB

  // ---- prep ----
  if (keepSEb) {
    k_prep<<<dim3(14784), dim3(256), 0, stream>>>(SE, SEb, ws_, wsbT, wd1, wd1T, wd, wdT,
                                                  wa, waT, whs, whsT, w_ih, w_ihb, w_hh, w_hhb,
                                                  sr, srb, asp, aspb);
    k_gemm_se<<<dim3(1536), dim3(256), 0, stream>>>(SEb, wsbT, Seb);
  } else {
    k_conv_bf16<<<dim3(12288), dim3(256), 0, stream>>>(SE, SEb, 3145728);
    k_transpose_ws<<<dim3(24, 24), dim3(256), 0, stream>>>(ws_, wsbT);
    k_gemm_se<<<dim3(1536), dim3(256), 0, stream>>>(SEb, wsbT, Seb);
    k_transpose4<<<dim3(24, 24, 4), dim3(256), 0, stream>>>(wd1, wd1T, wd, wdT, wa, waT, whs, whsT);
    k_conv4<<<dim3(1776), dim3(256), 0, stream>>>(w_ih, w_ihb, 221184, w_hh, w_hhb, 221184,
                                                  sr, srb, 6144, asp, aspb, 6144);
  }
  k_init2<<<dim3(6, 7), dim3(256), 0, stream>>>(srb, whsT, hA, hbA, wd1T, aspb, waT, Vp);

  const float* hcur = hA;
  const unsigned short* hbcur = hbA;
  for (int tl = 0; tl < 3; ++tl) {
    if (tl > 0)
      k_vpart<<<dim3(6, 6), dim3(256), 0, stream>>>(hbcur, wdT, aspb, waT, Vp);
    k_scores<<<dim3(32, 64), dim3(256), 0, stream>>>(Seb, Vp, wv, scores);
    if (keepSEb)
      k_at_sm_bf16<<<dim3(16, 64), dim3(192), 0, stream>>>(SEb, scores, mask, at_part);
    else
      k_at_sm_f32<<<dim3(16, 64), dim3(192), 0, stream>>>(SE, scores, mask, at_part);
    k_at_reduce<<<dim3(192), dim3(256), 0, stream>>>(at_part, atb);
    k_gates2<<<dim3(18, 2, 2), dim3(256), 0, stream>>>(atb, hbcur, w_ihb, w_hhb, gi2, gh2);
    float* hout = (tl == 2) ? out : ((hcur == hA) ? hB : hA);
    unsigned short* hbout = (hbcur == hbA) ? hbB : hbA;
    k_gru_elem2<<<dim3(192), dim3(256), 0, stream>>>(gi2, gh2, hcur, hout, hbout);
    hcur = hout;
    hbcur = hbout;
  }
}